// Round 7
// baseline (1424.259 us; speedup 1.0000x reference)
//
#include <hip/hip_runtime.h>

// GIN + virtual-node GNN, 5 layers.
// R7: agg chunked - grid 2048 blocks x ~25 contiguous nodes each (was 1
// node/block x 50000 blocks). Nodes are graph-sorted so gathers are local;
// chunking makes per-XCD L2 working set ~3.2MB < 4MB -> gather becomes L2-hit.
// Also amortizes per-block edge_W LDS staging 25x. Rest unchanged from R6.

#define EMB 128
#define NGR 512
#define NLAYER 5
static constexpr float BN_EPS = 1e-5f;

typedef __attribute__((ext_vector_type(8))) short short8v;  // 8 bf16 = 4 VGPR
typedef __attribute__((ext_vector_type(4))) float f32x4;

__device__ __forceinline__ ushort f2bf(float f) {
  union { float f; unsigned u; } c; c.f = f;
  return (ushort)((c.u + 0x7FFFu + ((c.u >> 16) & 1u)) >> 16);
}
__device__ __forceinline__ float bf2f(ushort h) {
  union { unsigned u; float f; } c; c.u = ((unsigned)h) << 16;
  return c.f;
}

// ---------------- setup kernels ----------------

__global__ void init_kernel(int* __restrict__ deg, int ndeg,
                            float* __restrict__ stats, int nstats,
                            float* __restrict__ vn, const float* __restrict__ vn_emb) {
  int idx = blockIdx.x * blockDim.x + threadIdx.x;
  if (idx < ndeg) deg[idx] = 0;
  if (idx < nstats) stats[idx] = 0.f;
  if (idx < NGR * EMB) vn[idx] = vn_emb[idx & (EMB - 1)];
}

__global__ void deg_kernel(const int* __restrict__ ei, int* __restrict__ deg, int E) {
  int e = blockIdx.x * blockDim.x + threadIdx.x;
  if (e < E) atomicAdd(&deg[ei[E + e]], 1);
}

// ---- hierarchical prefix scan over deg[n] (2048 elems per 256-thr block) ----

__global__ void scan1_kernel(const int* __restrict__ deg, int* __restrict__ bsum, int n) {
  __shared__ int ws[4];
  int t = threadIdx.x;
  int base = blockIdx.x * 2048 + t * 8;
  int s = 0;
  #pragma unroll
  for (int i = 0; i < 8; ++i) {
    int idx = base + i;
    if (idx < n) s += deg[idx];
  }
  #pragma unroll
  for (int off = 32; off; off >>= 1) s += __shfl_down(s, off);
  if ((t & 63) == 0) ws[t >> 6] = s;
  __syncthreads();
  if (t == 0) bsum[blockIdx.x] = ws[0] + ws[1] + ws[2] + ws[3];
}

// single 64-thread block; nb <= 64. boff = exclusive scan; *row_n = total.
__global__ void scan2_kernel(const int* __restrict__ bsum, int* __restrict__ boff,
                             int* __restrict__ row_n, int nb) {
  int t = threadIdx.x;
  int mine = (t < nb) ? bsum[t] : 0;
  int v = mine;
  #pragma unroll
  for (int off = 1; off < 64; off <<= 1) {
    int u = __shfl_up(v, off);
    if (t >= off) v += u;
  }
  if (t < nb) boff[t] = v - mine;
  if (t == nb - 1) *row_n = v;
}

__global__ __launch_bounds__(256) void scan3_kernel(const int* __restrict__ deg,
                                                    const int* __restrict__ boff,
                                                    int* __restrict__ row_start,
                                                    int* __restrict__ cursor, int n) {
  __shared__ int lsum[256];
  int t = threadIdx.x;
  int base = blockIdx.x * 2048 + t * 8;
  int loc[8];
  int s = 0;
  #pragma unroll
  for (int i = 0; i < 8; ++i) {
    int idx = base + i;
    int d = (idx < n) ? deg[idx] : 0;
    loc[i] = s;
    s += d;
  }
  lsum[t] = s;
  __syncthreads();
  #pragma unroll
  for (int off = 1; off < 256; off <<= 1) {
    int v2 = (t >= off) ? lsum[t - off] : 0;
    __syncthreads();
    lsum[t] += v2;
    __syncthreads();
  }
  int toff = boff[blockIdx.x] + lsum[t] - s;  // exclusive across grid
  #pragma unroll
  for (int i = 0; i < 8; ++i) {
    int idx = base + i;
    if (idx < n) {
      int rs = toff + loc[i];
      row_start[idx] = rs;
      cursor[idx] = rs;
    }
  }
}

__global__ void fill_kernel(const int* __restrict__ ei, int* __restrict__ cursor,
                            int2* __restrict__ el, int E) {
  int e = blockIdx.x * blockDim.x + threadIdx.x;
  if (e < E) {
    int d = ei[E + e];
    int pos = atomicAdd(&cursor[d], 1);
    el[pos] = make_int2(e, ei[e]);   // (edge id, src)
  }
}

// graph_start[g] = lower_bound(batch, g); batch is sorted. Handles empty graphs.
__global__ void bounds_kernel(const int* __restrict__ batch, int* __restrict__ gstart,
                              int n, int ng) {
  int g = blockIdx.x * blockDim.x + threadIdx.x;
  if (g > ng) return;
  int lo = 0, hi = n;
  while (lo < hi) {
    int mid = (lo + hi) >> 1;
    if (batch[mid] < g) lo = mid + 1; else hi = mid;
  }
  gstart[g] = lo;
}

// W [L][K][N] -> Wth/Wtl [L][N][K] (transpose + bf16 hi/lo split), per flat idx
__global__ void wtrans_kernel(const float* __restrict__ W, ushort* __restrict__ Wth,
                              ushort* __restrict__ Wtl, int K, int N, int total) {
  int idx = blockIdx.x * blockDim.x + threadIdx.x;
  if (idx >= total) return;
  int kk = idx % K;
  int t = idx / K;
  int nn = t % N;
  int l = t / N;
  float v = W[((size_t)l * K + kk) * N + nn];
  ushort h = f2bf(v);
  Wth[idx] = h;
  Wtl[idx] = f2bf(v - bf2f(h));
}

// h0 = x @ node_W + node_b   (K=9, N=128)
__global__ void encoder_kernel(const float* __restrict__ x, const float* __restrict__ W,
                               const float* __restrict__ b, float* __restrict__ h0, int n) {
  __shared__ float Ws[9][EMB];
  __shared__ float bs[EMB];
  int t = threadIdx.x;
  if (t < EMB) {
    #pragma unroll
    for (int k = 0; k < 9; ++k) Ws[k][t] = W[k * EMB + t];
    bs[t] = b[t];
  }
  __syncthreads();
  int total = n * EMB;
  for (int idx = blockIdx.x * blockDim.x + t; idx < total; idx += gridDim.x * blockDim.x) {
    int i = idx >> 7, j = idx & 127;
    const float* xr = x + i * 9;
    float acc = bs[j];
    #pragma unroll
    for (int k = 0; k < 9; ++k) acc = fmaf(xr[k], Ws[k][j], acc);
    h0[idx] = acc;
  }
}

// ---------------- per-layer kernels ----------------

// h_in = (RAW ? src : relu(bn2(src))) + vn[batch]
template <bool RAW>
__global__ void hin_kernel(const float* __restrict__ src, const float* __restrict__ vn,
                           const int* __restrict__ batch, const float* __restrict__ s2raw,
                           const float* __restrict__ g2, const float* __restrict__ b2,
                           float* __restrict__ h_in, int n) {
  __shared__ float sc[EMB], sh[EMB];
  if (!RAW) {
    int j = threadIdx.x;
    if (j < EMB) {
      float s = s2raw[j], q = s2raw[EMB + j];
      float mean = s / (float)n;
      float var = q / (float)n - mean * mean;
      float scl = g2[j] * rsqrtf(var + BN_EPS);
      sc[j] = scl;
      sh[j] = b2[j] - mean * scl;
    }
    __syncthreads();
  }
  int total = n * EMB;
  for (int idx = blockIdx.x * blockDim.x + threadIdx.x; idx < total; idx += gridDim.x * blockDim.x) {
    int i = idx >> 7, j = idx & 127;
    float v = src[idx];
    if (!RAW) v = fmaxf(fmaf(v, sc[j], sh[j]), 0.f);
    h_in[idx] = v + vn[batch[i] * EMB + j];
  }
}

// final output: d_out = bn2(t2)  (no relu, layer L-1)
__global__ void out_kernel(const float* __restrict__ t2, const float* __restrict__ s2raw,
                           const float* __restrict__ g2, const float* __restrict__ b2,
                           float* __restrict__ out, int n) {
  __shared__ float sc[EMB], sh[EMB];
  int j0 = threadIdx.x;
  if (j0 < EMB) {
    float s = s2raw[j0], q = s2raw[EMB + j0];
    float mean = s / (float)n;
    float var = q / (float)n - mean * mean;
    float scl = g2[j0] * rsqrtf(var + BN_EPS);
    sc[j0] = scl;
    sh[j0] = b2[j0] - mean * scl;
  }
  __syncthreads();
  int total = n * EMB;
  for (int idx = blockIdx.x * blockDim.x + threadIdx.x; idx < total; idx += gridDim.x * blockDim.x) {
    int j = idx & 127;
    out[idx] = fmaf(t2[idx], sc[j], sh[j]);
  }
}

// vnsum[g] = vn[g] + sum_{i in graph g} h_in[i]   (batch sorted -> contiguous range)
__global__ void vnsum_kernel(const float* __restrict__ h_in, const int* __restrict__ gstart,
                             const float* __restrict__ vn, float* __restrict__ vnsum) {
  int g = blockIdx.x;
  int j = threadIdx.x;
  int s0 = gstart[g], s1 = gstart[g + 1];
  float acc = vn[g * EMB + j];
  for (int i = s0; i < s1; ++i) acc += h_in[i * EMB + j];
  vnsum[g * EMB + j] = acc;
}

// t_pre[i] = (1+eps)*h_in[i] + sum_{e: dst=i} relu(h_in[src(e)] + edge_attr[e] @ eW + eb)
// Chunked: each block owns a contiguous node range (graph-sorted -> local
// gathers, per-XCD L2-resident). 4-wide unrolled edge loop.
__global__ __launch_bounds__(128) void agg_kernel(
    const float* __restrict__ h_in, const int* __restrict__ row_start,
    const int2* __restrict__ el,
    const float* __restrict__ edge_attr, const float* __restrict__ eW,
    const float* __restrict__ eb, const float* __restrict__ eps_p, int l,
    float* __restrict__ t_pre, int n, int npb) {
  __shared__ float W[10][EMB];
  __shared__ float bia[EMB];
  int j = threadIdx.x;  // 128
  #pragma unroll
  for (int k = 0; k < 10; ++k) W[k][j] = eW[k * EMB + j];
  bia[j] = eb[j];
  float epsv = 1.f + eps_p[l];
  __syncthreads();
  int i0 = blockIdx.x * npb;
  int i1 = min(n, i0 + npb);
  for (int i = i0; i < i1; ++i) {
    int s0 = row_start[i], s1 = row_start[i + 1];
    float acc = epsv * h_in[(size_t)i * EMB + j];
    int p = s0;
    for (; p + 4 <= s1; p += 4) {
      int2 e0 = el[p], e1 = el[p + 1], e2 = el[p + 2], e3 = el[p + 3];
      float hv0 = h_in[(size_t)e0.y * EMB + j];
      float hv1 = h_in[(size_t)e1.y * EMB + j];
      float hv2 = h_in[(size_t)e2.y * EMB + j];
      float hv3 = h_in[(size_t)e3.y * EMB + j];
      const float* ea0 = edge_attr + (size_t)e0.x * 10;
      const float* ea1 = edge_attr + (size_t)e1.x * 10;
      const float* ea2 = edge_attr + (size_t)e2.x * 10;
      const float* ea3 = edge_attr + (size_t)e3.x * 10;
      float v0 = bia[j], v1 = bia[j], v2 = bia[j], v3 = bia[j];
      #pragma unroll
      for (int k = 0; k < 10; ++k) {
        float w = W[k][j];
        v0 = fmaf(ea0[k], w, v0);
        v1 = fmaf(ea1[k], w, v1);
        v2 = fmaf(ea2[k], w, v2);
        v3 = fmaf(ea3[k], w, v3);
      }
      acc += fmaxf(v0 + hv0, 0.f) + fmaxf(v1 + hv1, 0.f) +
             fmaxf(v2 + hv2, 0.f) + fmaxf(v3 + hv3, 0.f);
    }
    for (; p < s1; ++p) {
      int2 e0 = el[p];
      float hv0 = h_in[(size_t)e0.y * EMB + j];
      const float* ea0 = edge_attr + (size_t)e0.x * 10;
      float v0 = bia[j];
      #pragma unroll
      for (int k = 0; k < 10; ++k) v0 = fmaf(ea0[k], W[k][j], v0);
      acc += fmaxf(v0 + hv0, 0.f);
    }
    t_pre[(size_t)i * EMB + j] = acc;
  }
}

// ---------------- bf16x3 split-MFMA GEMM (unchanged from R4) ----------------
template <int KT, int NT, bool BN_A, bool STATS>
__global__ __launch_bounds__(256) void gemm_mfma(
    const float* __restrict__ A, const ushort* __restrict__ Bth,
    const ushort* __restrict__ Btl, const float* __restrict__ bias,
    float* __restrict__ C, int M,
    const float* __restrict__ bnraw, const float* __restrict__ bng,
    const float* __restrict__ bnb, float* __restrict__ statraw) {
  constexpr int BM = 128, BN = 128, BK = 32;
  constexpr int LDK = BK + 8;
  constexpr int KSTEPS = KT / BK;
  __shared__ ushort Ah[BM][LDK], Al[BM][LDK];
  __shared__ ushort Bh[BN][LDK], Bl[BN][LDK];
  __shared__ float red[8][BN], redq[8][BN];
  constexpr int SCN = BN_A ? KT : 1;
  __shared__ float scS[SCN], shS[SCN];

  int tid = threadIdx.x;
  if (BN_A) {
    for (int k = tid; k < KT; k += 256) {
      float s = bnraw[k], q = bnraw[KT + k];
      float mean = s / (float)M;
      float var = q / (float)M - mean * mean;
      float scl = bng[k] * rsqrtf(var + BN_EPS);
      scS[k] = scl;
      shS[k] = bnb[k] - mean * scl;
    }
  }

  int wv = tid >> 6, lane = tid & 63;
  int wr = wv >> 1, wc = wv & 1;
  int lr = lane & 15, kg = lane >> 4;
  int bm0 = blockIdx.x * BM;
  int gc0 = blockIdx.y * BN;

  int sr = tid >> 1;
  int skq = (tid & 1) * 16;

  f32x4 acc[4][4];
  #pragma unroll
  for (int fm = 0; fm < 4; ++fm)
    #pragma unroll
    for (int fn = 0; fn < 4; ++fn) {
      float b = bias[gc0 + wc * 64 + fn * 16 + lr];
      acc[fm][fn][0] = b; acc[fm][fn][1] = b; acc[fm][fn][2] = b; acc[fm][fn][3] = b;
    }

  for (int kt = 0; kt < KSTEPS; ++kt) {
    __syncthreads();
    {
      int grow = bm0 + sr;
      const float* ap = A + (size_t)grow * KT + kt * BK + skq;
      short8v ah0, al0, ah1, al1;
      #pragma unroll
      for (int u = 0; u < 4; ++u) {
        float4 v = (grow < M) ? *reinterpret_cast<const float4*>(ap + u * 4)
                              : make_float4(0.f, 0.f, 0.f, 0.f);
        if (BN_A) {
          int gk = kt * BK + skq + u * 4;
          v.x = fmaxf(fmaf(v.x, scS[gk + 0], shS[gk + 0]), 0.f);
          v.y = fmaxf(fmaf(v.y, scS[gk + 1], shS[gk + 1]), 0.f);
          v.z = fmaxf(fmaf(v.z, scS[gk + 2], shS[gk + 2]), 0.f);
          v.w = fmaxf(fmaf(v.w, scS[gk + 3], shS[gk + 3]), 0.f);
        }
        float vv0 = v.x, vv1 = v.y, vv2 = v.z, vv3 = v.w;
        ushort h0 = f2bf(vv0), h1 = f2bf(vv1), h2 = f2bf(vv2), h3 = f2bf(vv3);
        ushort w0 = f2bf(vv0 - bf2f(h0)), w1 = f2bf(vv1 - bf2f(h1));
        ushort w2 = f2bf(vv2 - bf2f(h2)), w3 = f2bf(vv3 - bf2f(h3));
        if (u < 2) {
          ah0[u * 4 + 0] = (short)h0; ah0[u * 4 + 1] = (short)h1;
          ah0[u * 4 + 2] = (short)h2; ah0[u * 4 + 3] = (short)h3;
          al0[u * 4 + 0] = (short)w0; al0[u * 4 + 1] = (short)w1;
          al0[u * 4 + 2] = (short)w2; al0[u * 4 + 3] = (short)w3;
        } else {
          ah1[(u - 2) * 4 + 0] = (short)h0; ah1[(u - 2) * 4 + 1] = (short)h1;
          ah1[(u - 2) * 4 + 2] = (short)h2; ah1[(u - 2) * 4 + 3] = (short)h3;
          al1[(u - 2) * 4 + 0] = (short)w0; al1[(u - 2) * 4 + 1] = (short)w1;
          al1[(u - 2) * 4 + 2] = (short)w2; al1[(u - 2) * 4 + 3] = (short)w3;
        }
      }
      *(short8v*)&Ah[sr][skq] = ah0;
      *(short8v*)&Ah[sr][skq + 8] = ah1;
      *(short8v*)&Al[sr][skq] = al0;
      *(short8v*)&Al[sr][skq + 8] = al1;
    }
    {
      const ushort* bph = Bth + (size_t)(gc0 + sr) * KT + kt * BK + skq;
      const ushort* bpl = Btl + (size_t)(gc0 + sr) * KT + kt * BK + skq;
      *(short8v*)&Bh[sr][skq] = *(const short8v*)bph;
      *(short8v*)&Bh[sr][skq + 8] = *(const short8v*)(bph + 8);
      *(short8v*)&Bl[sr][skq] = *(const short8v*)bpl;
      *(short8v*)&Bl[sr][skq + 8] = *(const short8v*)(bpl + 8);
    }
    __syncthreads();
    short8v a_h[4], a_l[4], b_h[4], b_l[4];
    #pragma unroll
    for (int f = 0; f < 4; ++f) {
      a_h[f] = *(const short8v*)&Ah[wr * 64 + f * 16 + lr][kg * 8];
      a_l[f] = *(const short8v*)&Al[wr * 64 + f * 16 + lr][kg * 8];
      b_h[f] = *(const short8v*)&Bh[wc * 64 + f * 16 + lr][kg * 8];
      b_l[f] = *(const short8v*)&Bl[wc * 64 + f * 16 + lr][kg * 8];
    }
    #pragma unroll
    for (int fm = 0; fm < 4; ++fm)
      #pragma unroll
      for (int fn = 0; fn < 4; ++fn) {
        acc[fm][fn] = __builtin_amdgcn_mfma_f32_16x16x32_bf16(a_h[fm], b_h[fn], acc[fm][fn], 0, 0, 0);
        acc[fm][fn] = __builtin_amdgcn_mfma_f32_16x16x32_bf16(a_h[fm], b_l[fn], acc[fm][fn], 0, 0, 0);
        acc[fm][fn] = __builtin_amdgcn_mfma_f32_16x16x32_bf16(a_l[fm], b_h[fn], acc[fm][fn], 0, 0, 0);
      }
  }

  #pragma unroll
  for (int fm = 0; fm < 4; ++fm) {
    int rb = bm0 + wr * 64 + fm * 16 + kg * 4;
    #pragma unroll
    for (int i = 0; i < 4; ++i) {
      int grow = rb + i;
      if (grow < M) {
        float* cp = C + (size_t)grow * NT + gc0 + wc * 64 + lr;
        #pragma unroll
        for (int fn = 0; fn < 4; ++fn) cp[fn * 16] = acc[fm][fn][i];
      }
    }
  }

  if (STATS) {
    #pragma unroll
    for (int fn = 0; fn < 4; ++fn) {
      float s = 0.f, q = 0.f;
      #pragma unroll
      for (int fm = 0; fm < 4; ++fm) {
        int rb = bm0 + wr * 64 + fm * 16 + kg * 4;
        #pragma unroll
        for (int i = 0; i < 4; ++i) {
          if (rb + i < M) {
            float v = acc[fm][fn][i];
            s += v;
            q = fmaf(v, v, q);
          }
        }
      }
      red[wr * 4 + kg][wc * 64 + fn * 16 + lr] = s;
      redq[wr * 4 + kg][wc * 64 + fn * 16 + lr] = q;
    }
    __syncthreads();
    if (tid < BN) {
      float s = 0.f, q = 0.f;
      #pragma unroll
      for (int r2 = 0; r2 < 8; ++r2) {
        s += red[r2][tid];
        q += redq[r2][tid];
      }
      int gcol = gc0 + tid;
      atomicAdd(&statraw[gcol], s);
      atomicAdd(&statraw[NT + gcol], q);
    }
  }
}

// ---------------- virtual-node MLP (tiny: 512 rows) ----------------

__global__ void vmlp1_kernel(const float* __restrict__ vtmp, const float* __restrict__ W,
                             const float* __restrict__ b, float* __restrict__ u1,
                             float* __restrict__ vs1raw) {
  __shared__ float a[EMB];
  int g = blockIdx.x;
  int j = threadIdx.x;  // 256
  if (j < EMB) a[j] = vtmp[g * EMB + j];
  __syncthreads();
  float acc = b[j];
  #pragma unroll 8
  for (int k = 0; k < EMB; ++k) acc = fmaf(a[k], W[k * 256 + j], acc);
  u1[g * 256 + j] = acc;
  atomicAdd(&vs1raw[j], acc);
  atomicAdd(&vs1raw[256 + j], acc * acc);
}

__global__ void vmlp2_kernel(const float* __restrict__ u1, const float* __restrict__ vs1raw,
                             const float* __restrict__ g1, const float* __restrict__ b1,
                             const float* __restrict__ W, const float* __restrict__ b2,
                             float* __restrict__ u2, float* __restrict__ vs2raw) {
  __shared__ float a[256];
  __shared__ float sc[256], sh[256];
  int g = blockIdx.x;
  int j = threadIdx.x;  // 128
  for (int k = j; k < 256; k += EMB) {
    float s = vs1raw[k], q = vs1raw[256 + k];
    float mean = s / (float)NGR;
    float var = q / (float)NGR - mean * mean;
    float scl = g1[k] * rsqrtf(var + BN_EPS);
    sc[k] = scl;
    sh[k] = b1[k] - mean * scl;
  }
  __syncthreads();
  for (int k = j; k < 256; k += EMB)
    a[k] = fmaxf(fmaf(u1[g * 256 + k], sc[k], sh[k]), 0.f);
  __syncthreads();
  float acc = b2[j];
  #pragma unroll 8
  for (int k = 0; k < 256; ++k) acc = fmaf(a[k], W[k * EMB + j], acc);
  u2[g * EMB + j] = acc;
  atomicAdd(&vs2raw[j], acc);
  atomicAdd(&vs2raw[EMB + j], acc * acc);
}

__global__ void vnupd_kernel(const float* __restrict__ u2, const float* __restrict__ vs2raw,
                             const float* __restrict__ g2, const float* __restrict__ b2,
                             float* __restrict__ vn) {
  __shared__ float sc[EMB], sh[EMB];
  int g = blockIdx.x;
  int j = threadIdx.x;  // 128
  {
    float s = vs2raw[j], q = vs2raw[EMB + j];
    float mean = s / (float)NGR;
    float var = q / (float)NGR - mean * mean;
    float scl = g2[j] * rsqrtf(var + BN_EPS);
    sc[j] = scl;
    sh[j] = b2[j] - mean * scl;
  }
  __syncthreads();
  vn[g * EMB + j] = fmaxf(fmaf(u2[g * EMB + j], sc[j], sh[j]), 0.f);
}

// ---------------- host launcher ----------------

extern "C" void kernel_launch(void* const* d_in, const int* in_sizes, int n_in,
                              void* d_out, int out_size, void* d_ws, size_t ws_size,
                              hipStream_t stream) {
  const float* x        = (const float*)d_in[0];
  const int*   ei       = (const int*)d_in[1];
  const float* eattr    = (const float*)d_in[2];
  const int*   batch    = (const int*)d_in[3];
  const float* node_W   = (const float*)d_in[4];
  const float* node_b   = (const float*)d_in[5];
  const float* vn_emb   = (const float*)d_in[6];
  const float* eps      = (const float*)d_in[7];
  const float* edge_W   = (const float*)d_in[8];
  const float* edge_b   = (const float*)d_in[9];
  const float* conv_W1  = (const float*)d_in[10];
  const float* conv_b1  = (const float*)d_in[11];
  const float* cbn_g    = (const float*)d_in[12];
  const float* cbn_b    = (const float*)d_in[13];
  const float* conv_W2  = (const float*)d_in[14];
  const float* conv_b2  = (const float*)d_in[15];
  const float* bn_g     = (const float*)d_in[16];
  const float* bn_b     = (const float*)d_in[17];
  const float* vW1      = (const float*)d_in[18];
  const float* vb1      = (const float*)d_in[19];
  const float* vbn1_g   = (const float*)d_in[20];
  const float* vbn1_b   = (const float*)d_in[21];
  const float* vW2      = (const float*)d_in[22];
  const float* vb2      = (const float*)d_in[23];
  const float* vbn2_g   = (const float*)d_in[24];
  const float* vbn2_b   = (const float*)d_in[25];

  const int n = in_sizes[0] / 9;   // 50000
  const int E = in_sizes[1] / 2;   // 600000
  const int nb = (n + 2047) / 2048;

  // -------- workspace carve (aligned 256B) --------
  char* p = (char*)d_ws;
  auto carve = [&](size_t bytes) {
    char* r = p;
    p += (bytes + 255) & ~(size_t)255;
    return r;
  };
  float* tpre   = (float*)carve((size_t)n * EMB * 4);      // aliased: h0 then t_pre
  float* h_in   = (float*)carve((size_t)n * EMB * 4);
  float* t1     = (float*)carve((size_t)n * 256 * 4);
  float* t2     = (float*)carve((size_t)n * EMB * 4);
  float* vn     = (float*)carve((size_t)NGR * EMB * 4);
  float* vnsum  = (float*)carve((size_t)NGR * EMB * 4);
  float* u1     = (float*)carve((size_t)NGR * 256 * 4);
  float* u2     = (float*)carve((size_t)NGR * EMB * 4);
  float* stats  = (float*)carve((size_t)NLAYER * 1536 * 4);
  int* deg      = (int*)carve((size_t)n * 4);
  int* rstart   = (int*)carve((size_t)(n + 1) * 4);
  int* cursor   = (int*)carve((size_t)n * 4);
  int2* el      = (int2*)carve((size_t)E * 8);
  int* gstart   = (int*)carve((size_t)(NGR + 1) * 4);
  int* bsum     = (int*)carve((size_t)64 * 4);
  int* boff     = (int*)carve((size_t)64 * 4);
  ushort* wt1h  = (ushort*)carve((size_t)NLAYER * 256 * 128 * 2);
  ushort* wt1l  = (ushort*)carve((size_t)NLAYER * 256 * 128 * 2);
  ushort* wt2h  = (ushort*)carve((size_t)NLAYER * 128 * 256 * 2);
  ushort* wt2l  = (ushort*)carve((size_t)NLAYER * 128 * 256 * 2);
  float* h0     = tpre;  // alias: h0 consumed (by l=0 h_in) before t_pre written

  auto s1  = [&](int l) { return stats + (size_t)l * 1536; };
  auto s2  = [&](int l) { return stats + (size_t)l * 1536 + 512; };
  auto vs1 = [&](int l) { return stats + (size_t)l * 1536 + 768; };
  auto vs2 = [&](int l) { return stats + (size_t)l * 1536 + 1280; };

  // -------- setup --------
  init_kernel<<<(NGR * EMB + 255) / 256, 256, 0, stream>>>(deg, n, stats, NLAYER * 1536, vn, vn_emb);
  deg_kernel<<<(E + 255) / 256, 256, 0, stream>>>(ei, deg, E);
  scan1_kernel<<<nb, 256, 0, stream>>>(deg, bsum, n);
  scan2_kernel<<<1, 64, 0, stream>>>(bsum, boff, rstart + n, nb);
  scan3_kernel<<<nb, 256, 0, stream>>>(deg, boff, rstart, cursor, n);
  fill_kernel<<<(E + 255) / 256, 256, 0, stream>>>(ei, cursor, el, E);
  bounds_kernel<<<(NGR + 1 + 255) / 256, 256, 0, stream>>>(batch, gstart, n, NGR);
  {
    int tot1 = NLAYER * 128 * 256;   // conv_W1: K=128, N=256
    wtrans_kernel<<<(tot1 + 255) / 256, 256, 0, stream>>>(conv_W1, wt1h, wt1l, 128, 256, tot1);
    int tot2 = NLAYER * 256 * 128;   // conv_W2: K=256, N=128
    wtrans_kernel<<<(tot2 + 255) / 256, 256, 0, stream>>>(conv_W2, wt2h, wt2l, 256, 128, tot2);
  }
  encoder_kernel<<<2048, 256, 0, stream>>>(x, node_W, node_b, h0, n);

  const int mtiles = (n + 127) / 128;
  const int AGG_BLOCKS = 2048;
  const int npb = (n + AGG_BLOCKS - 1) / AGG_BLOCKS;

  for (int l = 0; l < NLAYER; ++l) {
    if (l == 0)
      hin_kernel<true><<<4096, 256, 0, stream>>>(h0, vn, batch, nullptr, nullptr, nullptr, h_in, n);
    else
      hin_kernel<false><<<4096, 256, 0, stream>>>(t2, vn, batch, s2(l - 1),
                                                  bn_g + (size_t)(l - 1) * EMB,
                                                  bn_b + (size_t)(l - 1) * EMB, h_in, n);
    if (l < NLAYER - 1)
      vnsum_kernel<<<NGR, EMB, 0, stream>>>(h_in, gstart, vn, vnsum);

    agg_kernel<<<AGG_BLOCKS, EMB, 0, stream>>>(h_in, rstart, el, eattr,
                                               edge_W + (size_t)l * 10 * EMB,
                                               edge_b + (size_t)l * EMB, eps, l, tpre, n, npb);

    gemm_mfma<128, 256, false, true><<<dim3(mtiles, 2), 256, 0, stream>>>(
        tpre, wt1h + (size_t)l * 256 * 128, wt1l + (size_t)l * 256 * 128,
        conv_b1 + (size_t)l * 256, t1, n, nullptr, nullptr, nullptr, s1(l));

    gemm_mfma<256, 128, true, true><<<dim3(mtiles, 1), 256, 0, stream>>>(
        t1, wt2h + (size_t)l * 128 * 256, wt2l + (size_t)l * 128 * 256,
        conv_b2 + (size_t)l * 128, t2, n,
        s1(l), cbn_g + (size_t)l * 256, cbn_b + (size_t)l * 256, s2(l));

    if (l < NLAYER - 1) {
      vmlp1_kernel<<<NGR, 256, 0, stream>>>(vnsum, vW1 + (size_t)l * 128 * 256,
                                            vb1 + (size_t)l * 256, u1, vs1(l));
      vmlp2_kernel<<<NGR, EMB, 0, stream>>>(u1, vs1(l), vbn1_g + (size_t)l * 256,
                                            vbn1_b + (size_t)l * 256,
                                            vW2 + (size_t)l * 256 * 128,
                                            vb2 + (size_t)l * EMB, u2, vs2(l));
      vnupd_kernel<<<NGR, EMB, 0, stream>>>(u2, vs2(l), vbn2_g + (size_t)l * EMB,
                                            vbn2_b + (size_t)l * EMB, vn);
    }
  }

  out_kernel<<<4096, 256, 0, stream>>>(t2, s2(NLAYER - 1),
                                       bn_g + (size_t)(NLAYER - 1) * EMB,
                                       bn_b + (size_t)(NLAYER - 1) * EMB,
                                       (float*)d_out, n);
}

// Round 8
// 1256.552 us; speedup vs baseline: 1.1335x; 1.1335x over previous
//
#include <hip/hip_runtime.h>

// GIN + virtual-node GNN, 5 layers.
// R8: agg reverted to 1 node/block (R7 chunking halved occupancy, no locality
// gain) + bijective XCD swizzle (m204): XCD x gets a contiguous ~n/8 node
// slice -> 3.2MB h_in slice per XCD L2 (4MB). Rest unchanged from R6.

#define EMB 128
#define NGR 512
#define NLAYER 5
static constexpr float BN_EPS = 1e-5f;

typedef __attribute__((ext_vector_type(8))) short short8v;  // 8 bf16 = 4 VGPR
typedef __attribute__((ext_vector_type(4))) float f32x4;

__device__ __forceinline__ ushort f2bf(float f) {
  union { float f; unsigned u; } c; c.f = f;
  return (ushort)((c.u + 0x7FFFu + ((c.u >> 16) & 1u)) >> 16);
}
__device__ __forceinline__ float bf2f(ushort h) {
  union { unsigned u; float f; } c; c.u = ((unsigned)h) << 16;
  return c.f;
}

// ---------------- setup kernels ----------------

__global__ void init_kernel(int* __restrict__ deg, int ndeg,
                            float* __restrict__ stats, int nstats,
                            float* __restrict__ vn, const float* __restrict__ vn_emb) {
  int idx = blockIdx.x * blockDim.x + threadIdx.x;
  if (idx < ndeg) deg[idx] = 0;
  if (idx < nstats) stats[idx] = 0.f;
  if (idx < NGR * EMB) vn[idx] = vn_emb[idx & (EMB - 1)];
}

__global__ void deg_kernel(const int* __restrict__ ei, int* __restrict__ deg, int E) {
  int e = blockIdx.x * blockDim.x + threadIdx.x;
  if (e < E) atomicAdd(&deg[ei[E + e]], 1);
}

// ---- hierarchical prefix scan over deg[n] (2048 elems per 256-thr block) ----

__global__ void scan1_kernel(const int* __restrict__ deg, int* __restrict__ bsum, int n) {
  __shared__ int ws[4];
  int t = threadIdx.x;
  int base = blockIdx.x * 2048 + t * 8;
  int s = 0;
  #pragma unroll
  for (int i = 0; i < 8; ++i) {
    int idx = base + i;
    if (idx < n) s += deg[idx];
  }
  #pragma unroll
  for (int off = 32; off; off >>= 1) s += __shfl_down(s, off);
  if ((t & 63) == 0) ws[t >> 6] = s;
  __syncthreads();
  if (t == 0) bsum[blockIdx.x] = ws[0] + ws[1] + ws[2] + ws[3];
}

// single 64-thread block; nb <= 64. boff = exclusive scan; *row_n = total.
__global__ void scan2_kernel(const int* __restrict__ bsum, int* __restrict__ boff,
                             int* __restrict__ row_n, int nb) {
  int t = threadIdx.x;
  int mine = (t < nb) ? bsum[t] : 0;
  int v = mine;
  #pragma unroll
  for (int off = 1; off < 64; off <<= 1) {
    int u = __shfl_up(v, off);
    if (t >= off) v += u;
  }
  if (t < nb) boff[t] = v - mine;
  if (t == nb - 1) *row_n = v;
}

__global__ __launch_bounds__(256) void scan3_kernel(const int* __restrict__ deg,
                                                    const int* __restrict__ boff,
                                                    int* __restrict__ row_start,
                                                    int* __restrict__ cursor, int n) {
  __shared__ int lsum[256];
  int t = threadIdx.x;
  int base = blockIdx.x * 2048 + t * 8;
  int loc[8];
  int s = 0;
  #pragma unroll
  for (int i = 0; i < 8; ++i) {
    int idx = base + i;
    int d = (idx < n) ? deg[idx] : 0;
    loc[i] = s;
    s += d;
  }
  lsum[t] = s;
  __syncthreads();
  #pragma unroll
  for (int off = 1; off < 256; off <<= 1) {
    int v2 = (t >= off) ? lsum[t - off] : 0;
    __syncthreads();
    lsum[t] += v2;
    __syncthreads();
  }
  int toff = boff[blockIdx.x] + lsum[t] - s;  // exclusive across grid
  #pragma unroll
  for (int i = 0; i < 8; ++i) {
    int idx = base + i;
    if (idx < n) {
      int rs = toff + loc[i];
      row_start[idx] = rs;
      cursor[idx] = rs;
    }
  }
}

__global__ void fill_kernel(const int* __restrict__ ei, int* __restrict__ cursor,
                            int2* __restrict__ el, int E) {
  int e = blockIdx.x * blockDim.x + threadIdx.x;
  if (e < E) {
    int d = ei[E + e];
    int pos = atomicAdd(&cursor[d], 1);
    el[pos] = make_int2(e, ei[e]);   // (edge id, src)
  }
}

// graph_start[g] = lower_bound(batch, g); batch is sorted. Handles empty graphs.
__global__ void bounds_kernel(const int* __restrict__ batch, int* __restrict__ gstart,
                              int n, int ng) {
  int g = blockIdx.x * blockDim.x + threadIdx.x;
  if (g > ng) return;
  int lo = 0, hi = n;
  while (lo < hi) {
    int mid = (lo + hi) >> 1;
    if (batch[mid] < g) lo = mid + 1; else hi = mid;
  }
  gstart[g] = lo;
}

// W [L][K][N] -> Wth/Wtl [L][N][K] (transpose + bf16 hi/lo split), per flat idx
__global__ void wtrans_kernel(const float* __restrict__ W, ushort* __restrict__ Wth,
                              ushort* __restrict__ Wtl, int K, int N, int total) {
  int idx = blockIdx.x * blockDim.x + threadIdx.x;
  if (idx >= total) return;
  int kk = idx % K;
  int t = idx / K;
  int nn = t % N;
  int l = t / N;
  float v = W[((size_t)l * K + kk) * N + nn];
  ushort h = f2bf(v);
  Wth[idx] = h;
  Wtl[idx] = f2bf(v - bf2f(h));
}

// h0 = x @ node_W + node_b   (K=9, N=128)
__global__ void encoder_kernel(const float* __restrict__ x, const float* __restrict__ W,
                               const float* __restrict__ b, float* __restrict__ h0, int n) {
  __shared__ float Ws[9][EMB];
  __shared__ float bs[EMB];
  int t = threadIdx.x;
  if (t < EMB) {
    #pragma unroll
    for (int k = 0; k < 9; ++k) Ws[k][t] = W[k * EMB + t];
    bs[t] = b[t];
  }
  __syncthreads();
  int total = n * EMB;
  for (int idx = blockIdx.x * blockDim.x + t; idx < total; idx += gridDim.x * blockDim.x) {
    int i = idx >> 7, j = idx & 127;
    const float* xr = x + i * 9;
    float acc = bs[j];
    #pragma unroll
    for (int k = 0; k < 9; ++k) acc = fmaf(xr[k], Ws[k][j], acc);
    h0[idx] = acc;
  }
}

// ---------------- per-layer kernels ----------------

// h_in = (RAW ? src : relu(bn2(src))) + vn[batch]
template <bool RAW>
__global__ void hin_kernel(const float* __restrict__ src, const float* __restrict__ vn,
                           const int* __restrict__ batch, const float* __restrict__ s2raw,
                           const float* __restrict__ g2, const float* __restrict__ b2,
                           float* __restrict__ h_in, int n) {
  __shared__ float sc[EMB], sh[EMB];
  if (!RAW) {
    int j = threadIdx.x;
    if (j < EMB) {
      float s = s2raw[j], q = s2raw[EMB + j];
      float mean = s / (float)n;
      float var = q / (float)n - mean * mean;
      float scl = g2[j] * rsqrtf(var + BN_EPS);
      sc[j] = scl;
      sh[j] = b2[j] - mean * scl;
    }
    __syncthreads();
  }
  int total = n * EMB;
  for (int idx = blockIdx.x * blockDim.x + threadIdx.x; idx < total; idx += gridDim.x * blockDim.x) {
    int i = idx >> 7, j = idx & 127;
    float v = src[idx];
    if (!RAW) v = fmaxf(fmaf(v, sc[j], sh[j]), 0.f);
    h_in[idx] = v + vn[batch[i] * EMB + j];
  }
}

// final output: d_out = bn2(t2)  (no relu, layer L-1)
__global__ void out_kernel(const float* __restrict__ t2, const float* __restrict__ s2raw,
                           const float* __restrict__ g2, const float* __restrict__ b2,
                           float* __restrict__ out, int n) {
  __shared__ float sc[EMB], sh[EMB];
  int j0 = threadIdx.x;
  if (j0 < EMB) {
    float s = s2raw[j0], q = s2raw[EMB + j0];
    float mean = s / (float)n;
    float var = q / (float)n - mean * mean;
    float scl = g2[j0] * rsqrtf(var + BN_EPS);
    sc[j0] = scl;
    sh[j0] = b2[j0] - mean * scl;
  }
  __syncthreads();
  int total = n * EMB;
  for (int idx = blockIdx.x * blockDim.x + threadIdx.x; idx < total; idx += gridDim.x * blockDim.x) {
    int j = idx & 127;
    out[idx] = fmaf(t2[idx], sc[j], sh[j]);
  }
}

// vnsum[g] = vn[g] + sum_{i in graph g} h_in[i]   (batch sorted -> contiguous range)
__global__ void vnsum_kernel(const float* __restrict__ h_in, const int* __restrict__ gstart,
                             const float* __restrict__ vn, float* __restrict__ vnsum) {
  int g = blockIdx.x;
  int j = threadIdx.x;
  int s0 = gstart[g], s1 = gstart[g + 1];
  float acc = vn[g * EMB + j];
  for (int i = s0; i < s1; ++i) acc += h_in[i * EMB + j];
  vnsum[g * EMB + j] = acc;
}

// t_pre[i] = (1+eps)*h_in[i] + sum_{e: dst=i} relu(h_in[src(e)] + edge_attr[e] @ eW + eb)
// 1 node/block (full occupancy) + bijective XCD swizzle: XCD x handles a
// contiguous ~n/8 node slice so its gathers stay in its 4MB L2 (m204).
__global__ __launch_bounds__(128) void agg_kernel(
    const float* __restrict__ h_in, const int* __restrict__ row_start,
    const int2* __restrict__ el,
    const float* __restrict__ edge_attr, const float* __restrict__ eW,
    const float* __restrict__ eb, const float* __restrict__ eps_p, int l,
    float* __restrict__ t_pre, int n) {
  __shared__ float W[10][EMB];
  __shared__ float bia[EMB];
  int j = threadIdx.x;  // 128
  #pragma unroll
  for (int k = 0; k < 10; ++k) W[k][j] = eW[k * EMB + j];
  bia[j] = eb[j];
  float epsv = 1.f + eps_p[l];
  __syncthreads();

  // bijective XCD swizzle: block bid -> node i; XCD (bid&7) gets contiguous slice
  int bid = blockIdx.x;
  int q = n >> 3, r = n & 7;
  int xcd = bid & 7;
  int i = (xcd < r ? xcd * (q + 1) : r * (q + 1) + (xcd - r) * q) + (bid >> 3);
  if (i >= n) return;

  int s0 = row_start[i], s1 = row_start[i + 1];
  float acc = epsv * h_in[(size_t)i * EMB + j];
  int p = s0;
  for (; p + 4 <= s1; p += 4) {
    int2 e0 = el[p], e1 = el[p + 1], e2 = el[p + 2], e3 = el[p + 3];
    float hv0 = h_in[(size_t)e0.y * EMB + j];
    float hv1 = h_in[(size_t)e1.y * EMB + j];
    float hv2 = h_in[(size_t)e2.y * EMB + j];
    float hv3 = h_in[(size_t)e3.y * EMB + j];
    const float* ea0 = edge_attr + (size_t)e0.x * 10;
    const float* ea1 = edge_attr + (size_t)e1.x * 10;
    const float* ea2 = edge_attr + (size_t)e2.x * 10;
    const float* ea3 = edge_attr + (size_t)e3.x * 10;
    float v0 = bia[j], v1 = bia[j], v2 = bia[j], v3 = bia[j];
    #pragma unroll
    for (int k = 0; k < 10; ++k) {
      float w = W[k][j];
      v0 = fmaf(ea0[k], w, v0);
      v1 = fmaf(ea1[k], w, v1);
      v2 = fmaf(ea2[k], w, v2);
      v3 = fmaf(ea3[k], w, v3);
    }
    acc += fmaxf(v0 + hv0, 0.f) + fmaxf(v1 + hv1, 0.f) +
           fmaxf(v2 + hv2, 0.f) + fmaxf(v3 + hv3, 0.f);
  }
  for (; p < s1; ++p) {
    int2 e0 = el[p];
    float hv0 = h_in[(size_t)e0.y * EMB + j];
    const float* ea0 = edge_attr + (size_t)e0.x * 10;
    float v0 = bia[j];
    #pragma unroll
    for (int k = 0; k < 10; ++k) v0 = fmaf(ea0[k], W[k][j], v0);
    acc += fmaxf(v0 + hv0, 0.f);
  }
  t_pre[(size_t)i * EMB + j] = acc;
}

// ---------------- bf16x3 split-MFMA GEMM (unchanged from R4) ----------------
template <int KT, int NT, bool BN_A, bool STATS>
__global__ __launch_bounds__(256) void gemm_mfma(
    const float* __restrict__ A, const ushort* __restrict__ Bth,
    const ushort* __restrict__ Btl, const float* __restrict__ bias,
    float* __restrict__ C, int M,
    const float* __restrict__ bnraw, const float* __restrict__ bng,
    const float* __restrict__ bnb, float* __restrict__ statraw) {
  constexpr int BM = 128, BN = 128, BK = 32;
  constexpr int LDK = BK + 8;
  constexpr int KSTEPS = KT / BK;
  __shared__ ushort Ah[BM][LDK], Al[BM][LDK];
  __shared__ ushort Bh[BN][LDK], Bl[BN][LDK];
  __shared__ float red[8][BN], redq[8][BN];
  constexpr int SCN = BN_A ? KT : 1;
  __shared__ float scS[SCN], shS[SCN];

  int tid = threadIdx.x;
  if (BN_A) {
    for (int k = tid; k < KT; k += 256) {
      float s = bnraw[k], q = bnraw[KT + k];
      float mean = s / (float)M;
      float var = q / (float)M - mean * mean;
      float scl = bng[k] * rsqrtf(var + BN_EPS);
      scS[k] = scl;
      shS[k] = bnb[k] - mean * scl;
    }
  }

  int wv = tid >> 6, lane = tid & 63;
  int wr = wv >> 1, wc = wv & 1;
  int lr = lane & 15, kg = lane >> 4;
  int bm0 = blockIdx.x * BM;
  int gc0 = blockIdx.y * BN;

  int sr = tid >> 1;
  int skq = (tid & 1) * 16;

  f32x4 acc[4][4];
  #pragma unroll
  for (int fm = 0; fm < 4; ++fm)
    #pragma unroll
    for (int fn = 0; fn < 4; ++fn) {
      float b = bias[gc0 + wc * 64 + fn * 16 + lr];
      acc[fm][fn][0] = b; acc[fm][fn][1] = b; acc[fm][fn][2] = b; acc[fm][fn][3] = b;
    }

  for (int kt = 0; kt < KSTEPS; ++kt) {
    __syncthreads();
    {
      int grow = bm0 + sr;
      const float* ap = A + (size_t)grow * KT + kt * BK + skq;
      short8v ah0, al0, ah1, al1;
      #pragma unroll
      for (int u = 0; u < 4; ++u) {
        float4 v = (grow < M) ? *reinterpret_cast<const float4*>(ap + u * 4)
                              : make_float4(0.f, 0.f, 0.f, 0.f);
        if (BN_A) {
          int gk = kt * BK + skq + u * 4;
          v.x = fmaxf(fmaf(v.x, scS[gk + 0], shS[gk + 0]), 0.f);
          v.y = fmaxf(fmaf(v.y, scS[gk + 1], shS[gk + 1]), 0.f);
          v.z = fmaxf(fmaf(v.z, scS[gk + 2], shS[gk + 2]), 0.f);
          v.w = fmaxf(fmaf(v.w, scS[gk + 3], shS[gk + 3]), 0.f);
        }
        float vv0 = v.x, vv1 = v.y, vv2 = v.z, vv3 = v.w;
        ushort h0 = f2bf(vv0), h1 = f2bf(vv1), h2 = f2bf(vv2), h3 = f2bf(vv3);
        ushort w0 = f2bf(vv0 - bf2f(h0)), w1 = f2bf(vv1 - bf2f(h1));
        ushort w2 = f2bf(vv2 - bf2f(h2)), w3 = f2bf(vv3 - bf2f(h3));
        if (u < 2) {
          ah0[u * 4 + 0] = (short)h0; ah0[u * 4 + 1] = (short)h1;
          ah0[u * 4 + 2] = (short)h2; ah0[u * 4 + 3] = (short)h3;
          al0[u * 4 + 0] = (short)w0; al0[u * 4 + 1] = (short)w1;
          al0[u * 4 + 2] = (short)w2; al0[u * 4 + 3] = (short)w3;
        } else {
          ah1[(u - 2) * 4 + 0] = (short)h0; ah1[(u - 2) * 4 + 1] = (short)h1;
          ah1[(u - 2) * 4 + 2] = (short)h2; ah1[(u - 2) * 4 + 3] = (short)h3;
          al1[(u - 2) * 4 + 0] = (short)w0; al1[(u - 2) * 4 + 1] = (short)w1;
          al1[(u - 2) * 4 + 2] = (short)w2; al1[(u - 2) * 4 + 3] = (short)w3;
        }
      }
      *(short8v*)&Ah[sr][skq] = ah0;
      *(short8v*)&Ah[sr][skq + 8] = ah1;
      *(short8v*)&Al[sr][skq] = al0;
      *(short8v*)&Al[sr][skq + 8] = al1;
    }
    {
      const ushort* bph = Bth + (size_t)(gc0 + sr) * KT + kt * BK + skq;
      const ushort* bpl = Btl + (size_t)(gc0 + sr) * KT + kt * BK + skq;
      *(short8v*)&Bh[sr][skq] = *(const short8v*)bph;
      *(short8v*)&Bh[sr][skq + 8] = *(const short8v*)(bph + 8);
      *(short8v*)&Bl[sr][skq] = *(const short8v*)bpl;
      *(short8v*)&Bl[sr][skq + 8] = *(const short8v*)(bpl + 8);
    }
    __syncthreads();
    short8v a_h[4], a_l[4], b_h[4], b_l[4];
    #pragma unroll
    for (int f = 0; f < 4; ++f) {
      a_h[f] = *(const short8v*)&Ah[wr * 64 + f * 16 + lr][kg * 8];
      a_l[f] = *(const short8v*)&Al[wr * 64 + f * 16 + lr][kg * 8];
      b_h[f] = *(const short8v*)&Bh[wc * 64 + f * 16 + lr][kg * 8];
      b_l[f] = *(const short8v*)&Bl[wc * 64 + f * 16 + lr][kg * 8];
    }
    #pragma unroll
    for (int fm = 0; fm < 4; ++fm)
      #pragma unroll
      for (int fn = 0; fn < 4; ++fn) {
        acc[fm][fn] = __builtin_amdgcn_mfma_f32_16x16x32_bf16(a_h[fm], b_h[fn], acc[fm][fn], 0, 0, 0);
        acc[fm][fn] = __builtin_amdgcn_mfma_f32_16x16x32_bf16(a_h[fm], b_l[fn], acc[fm][fn], 0, 0, 0);
        acc[fm][fn] = __builtin_amdgcn_mfma_f32_16x16x32_bf16(a_l[fm], b_h[fn], acc[fm][fn], 0, 0, 0);
      }
  }

  #pragma unroll
  for (int fm = 0; fm < 4; ++fm) {
    int rb = bm0 + wr * 64 + fm * 16 + kg * 4;
    #pragma unroll
    for (int i = 0; i < 4; ++i) {
      int grow = rb + i;
      if (grow < M) {
        float* cp = C + (size_t)grow * NT + gc0 + wc * 64 + lr;
        #pragma unroll
        for (int fn = 0; fn < 4; ++fn) cp[fn * 16] = acc[fm][fn][i];
      }
    }
  }

  if (STATS) {
    #pragma unroll
    for (int fn = 0; fn < 4; ++fn) {
      float s = 0.f, q = 0.f;
      #pragma unroll
      for (int fm = 0; fm < 4; ++fm) {
        int rb = bm0 + wr * 64 + fm * 16 + kg * 4;
        #pragma unroll
        for (int i = 0; i < 4; ++i) {
          if (rb + i < M) {
            float v = acc[fm][fn][i];
            s += v;
            q = fmaf(v, v, q);
          }
        }
      }
      red[wr * 4 + kg][wc * 64 + fn * 16 + lr] = s;
      redq[wr * 4 + kg][wc * 64 + fn * 16 + lr] = q;
    }
    __syncthreads();
    if (tid < BN) {
      float s = 0.f, q = 0.f;
      #pragma unroll
      for (int r2 = 0; r2 < 8; ++r2) {
        s += red[r2][tid];
        q += redq[r2][tid];
      }
      int gcol = gc0 + tid;
      atomicAdd(&statraw[gcol], s);
      atomicAdd(&statraw[NT + gcol], q);
    }
  }
}

// ---------------- virtual-node MLP (tiny: 512 rows) ----------------

__global__ void vmlp1_kernel(const float* __restrict__ vtmp, const float* __restrict__ W,
                             const float* __restrict__ b, float* __restrict__ u1,
                             float* __restrict__ vs1raw) {
  __shared__ float a[EMB];
  int g = blockIdx.x;
  int j = threadIdx.x;  // 256
  if (j < EMB) a[j] = vtmp[g * EMB + j];
  __syncthreads();
  float acc = b[j];
  #pragma unroll 8
  for (int k = 0; k < EMB; ++k) acc = fmaf(a[k], W[k * 256 + j], acc);
  u1[g * 256 + j] = acc;
  atomicAdd(&vs1raw[j], acc);
  atomicAdd(&vs1raw[256 + j], acc * acc);
}

__global__ void vmlp2_kernel(const float* __restrict__ u1, const float* __restrict__ vs1raw,
                             const float* __restrict__ g1, const float* __restrict__ b1,
                             const float* __restrict__ W, const float* __restrict__ b2,
                             float* __restrict__ u2, float* __restrict__ vs2raw) {
  __shared__ float a[256];
  __shared__ float sc[256], sh[256];
  int g = blockIdx.x;
  int j = threadIdx.x;  // 128
  for (int k = j; k < 256; k += EMB) {
    float s = vs1raw[k], q = vs1raw[256 + k];
    float mean = s / (float)NGR;
    float var = q / (float)NGR - mean * mean;
    float scl = g1[k] * rsqrtf(var + BN_EPS);
    sc[k] = scl;
    sh[k] = b1[k] - mean * scl;
  }
  __syncthreads();
  for (int k = j; k < 256; k += EMB)
    a[k] = fmaxf(fmaf(u1[g * 256 + k], sc[k], sh[k]), 0.f);
  __syncthreads();
  float acc = b2[j];
  #pragma unroll 8
  for (int k = 0; k < 256; ++k) acc = fmaf(a[k], W[k * EMB + j], acc);
  u2[g * EMB + j] = acc;
  atomicAdd(&vs2raw[j], acc);
  atomicAdd(&vs2raw[EMB + j], acc * acc);
}

__global__ void vnupd_kernel(const float* __restrict__ u2, const float* __restrict__ vs2raw,
                             const float* __restrict__ g2, const float* __restrict__ b2,
                             float* __restrict__ vn) {
  __shared__ float sc[EMB], sh[EMB];
  int g = blockIdx.x;
  int j = threadIdx.x;  // 128
  {
    float s = vs2raw[j], q = vs2raw[EMB + j];
    float mean = s / (float)NGR;
    float var = q / (float)NGR - mean * mean;
    float scl = g2[j] * rsqrtf(var + BN_EPS);
    sc[j] = scl;
    sh[j] = b2[j] - mean * scl;
  }
  __syncthreads();
  vn[g * EMB + j] = fmaxf(fmaf(u2[g * EMB + j], sc[j], sh[j]), 0.f);
}

// ---------------- host launcher ----------------

extern "C" void kernel_launch(void* const* d_in, const int* in_sizes, int n_in,
                              void* d_out, int out_size, void* d_ws, size_t ws_size,
                              hipStream_t stream) {
  const float* x        = (const float*)d_in[0];
  const int*   ei       = (const int*)d_in[1];
  const float* eattr    = (const float*)d_in[2];
  const int*   batch    = (const int*)d_in[3];
  const float* node_W   = (const float*)d_in[4];
  const float* node_b   = (const float*)d_in[5];
  const float* vn_emb   = (const float*)d_in[6];
  const float* eps      = (const float*)d_in[7];
  const float* edge_W   = (const float*)d_in[8];
  const float* edge_b   = (const float*)d_in[9];
  const float* conv_W1  = (const float*)d_in[10];
  const float* conv_b1  = (const float*)d_in[11];
  const float* cbn_g    = (const float*)d_in[12];
  const float* cbn_b    = (const float*)d_in[13];
  const float* conv_W2  = (const float*)d_in[14];
  const float* conv_b2  = (const float*)d_in[15];
  const float* bn_g     = (const float*)d_in[16];
  const float* bn_b     = (const float*)d_in[17];
  const float* vW1      = (const float*)d_in[18];
  const float* vb1      = (const float*)d_in[19];
  const float* vbn1_g   = (const float*)d_in[20];
  const float* vbn1_b   = (const float*)d_in[21];
  const float* vW2      = (const float*)d_in[22];
  const float* vb2      = (const float*)d_in[23];
  const float* vbn2_g   = (const float*)d_in[24];
  const float* vbn2_b   = (const float*)d_in[25];

  const int n = in_sizes[0] / 9;   // 50000
  const int E = in_sizes[1] / 2;   // 600000
  const int nb = (n + 2047) / 2048;

  // -------- workspace carve (aligned 256B) --------
  char* p = (char*)d_ws;
  auto carve = [&](size_t bytes) {
    char* r = p;
    p += (bytes + 255) & ~(size_t)255;
    return r;
  };
  float* tpre   = (float*)carve((size_t)n * EMB * 4);      // aliased: h0 then t_pre
  float* h_in   = (float*)carve((size_t)n * EMB * 4);
  float* t1     = (float*)carve((size_t)n * 256 * 4);
  float* t2     = (float*)carve((size_t)n * EMB * 4);
  float* vn     = (float*)carve((size_t)NGR * EMB * 4);
  float* vnsum  = (float*)carve((size_t)NGR * EMB * 4);
  float* u1     = (float*)carve((size_t)NGR * 256 * 4);
  float* u2     = (float*)carve((size_t)NGR * EMB * 4);
  float* stats  = (float*)carve((size_t)NLAYER * 1536 * 4);
  int* deg      = (int*)carve((size_t)n * 4);
  int* rstart   = (int*)carve((size_t)(n + 1) * 4);
  int* cursor   = (int*)carve((size_t)n * 4);
  int2* el      = (int2*)carve((size_t)E * 8);
  int* gstart   = (int*)carve((size_t)(NGR + 1) * 4);
  int* bsum     = (int*)carve((size_t)64 * 4);
  int* boff     = (int*)carve((size_t)64 * 4);
  ushort* wt1h  = (ushort*)carve((size_t)NLAYER * 256 * 128 * 2);
  ushort* wt1l  = (ushort*)carve((size_t)NLAYER * 256 * 128 * 2);
  ushort* wt2h  = (ushort*)carve((size_t)NLAYER * 128 * 256 * 2);
  ushort* wt2l  = (ushort*)carve((size_t)NLAYER * 128 * 256 * 2);
  float* h0     = tpre;  // alias: h0 consumed (by l=0 h_in) before t_pre written

  auto s1  = [&](int l) { return stats + (size_t)l * 1536; };
  auto s2  = [&](int l) { return stats + (size_t)l * 1536 + 512; };
  auto vs1 = [&](int l) { return stats + (size_t)l * 1536 + 768; };
  auto vs2 = [&](int l) { return stats + (size_t)l * 1536 + 1280; };

  // -------- setup --------
  init_kernel<<<(NGR * EMB + 255) / 256, 256, 0, stream>>>(deg, n, stats, NLAYER * 1536, vn, vn_emb);
  deg_kernel<<<(E + 255) / 256, 256, 0, stream>>>(ei, deg, E);
  scan1_kernel<<<nb, 256, 0, stream>>>(deg, bsum, n);
  scan2_kernel<<<1, 64, 0, stream>>>(bsum, boff, rstart + n, nb);
  scan3_kernel<<<nb, 256, 0, stream>>>(deg, boff, rstart, cursor, n);
  fill_kernel<<<(E + 255) / 256, 256, 0, stream>>>(ei, cursor, el, E);
  bounds_kernel<<<(NGR + 1 + 255) / 256, 256, 0, stream>>>(batch, gstart, n, NGR);
  {
    int tot1 = NLAYER * 128 * 256;   // conv_W1: K=128, N=256
    wtrans_kernel<<<(tot1 + 255) / 256, 256, 0, stream>>>(conv_W1, wt1h, wt1l, 128, 256, tot1);
    int tot2 = NLAYER * 256 * 128;   // conv_W2: K=256, N=128
    wtrans_kernel<<<(tot2 + 255) / 256, 256, 0, stream>>>(conv_W2, wt2h, wt2l, 256, 128, tot2);
  }
  encoder_kernel<<<2048, 256, 0, stream>>>(x, node_W, node_b, h0, n);

  const int mtiles = (n + 127) / 128;

  for (int l = 0; l < NLAYER; ++l) {
    if (l == 0)
      hin_kernel<true><<<4096, 256, 0, stream>>>(h0, vn, batch, nullptr, nullptr, nullptr, h_in, n);
    else
      hin_kernel<false><<<4096, 256, 0, stream>>>(t2, vn, batch, s2(l - 1),
                                                  bn_g + (size_t)(l - 1) * EMB,
                                                  bn_b + (size_t)(l - 1) * EMB, h_in, n);
    if (l < NLAYER - 1)
      vnsum_kernel<<<NGR, EMB, 0, stream>>>(h_in, gstart, vn, vnsum);

    agg_kernel<<<n, EMB, 0, stream>>>(h_in, rstart, el, eattr,
                                      edge_W + (size_t)l * 10 * EMB,
                                      edge_b + (size_t)l * EMB, eps, l, tpre, n);

    gemm_mfma<128, 256, false, true><<<dim3(mtiles, 2), 256, 0, stream>>>(
        tpre, wt1h + (size_t)l * 256 * 128, wt1l + (size_t)l * 256 * 128,
        conv_b1 + (size_t)l * 256, t1, n, nullptr, nullptr, nullptr, s1(l));

    gemm_mfma<256, 128, true, true><<<dim3(mtiles, 1), 256, 0, stream>>>(
        t1, wt2h + (size_t)l * 128 * 256, wt2l + (size_t)l * 128 * 256,
        conv_b2 + (size_t)l * 128, t2, n,
        s1(l), cbn_g + (size_t)l * 256, cbn_b + (size_t)l * 256, s2(l));

    if (l < NLAYER - 1) {
      vmlp1_kernel<<<NGR, 256, 0, stream>>>(vnsum, vW1 + (size_t)l * 128 * 256,
                                            vb1 + (size_t)l * 256, u1, vs1(l));
      vmlp2_kernel<<<NGR, EMB, 0, stream>>>(u1, vs1(l), vbn1_g + (size_t)l * 256,
                                            vbn1_b + (size_t)l * 256,
                                            vW2 + (size_t)l * 256 * 128,
                                            vb2 + (size_t)l * EMB, u2, vs2(l));
      vnupd_kernel<<<NGR, EMB, 0, stream>>>(u2, vs2(l), vbn2_g + (size_t)l * EMB,
                                            vbn2_b + (size_t)l * EMB, vn);
    }
  }

  out_kernel<<<4096, 256, 0, stream>>>(t2, s2(NLAYER - 1),
                                       bn_g + (size_t)(NLAYER - 1) * EMB,
                                       bn_b + (size_t)(NLAYER - 1) * EMB,
                                       (float*)d_out, n);
}